// Round 2
// baseline (105814.172 us; speedup 1.0000x reference)
//
#include <hip/hip_runtime.h>
#include <hip/hip_bf16.h>
#include <stdint.h>

#define T_STEPS 32768
#define HID 1024
#define FIN 256
#define NB 32            // scan blocks
#define RPB (HID / NB)   // rows per block = 32
#define RPW 8            // rows per wave (4 waves/block)

typedef unsigned long long ull;

// ---------------- Phase 1: xw[t][h] = sum_k x[t][k] * wih[h][k] ----------------
__global__ __launch_bounds__(256) void gemm_xw(const float* __restrict__ x,
                                               const float* __restrict__ wih,
                                               float* __restrict__ out) {
    __shared__ float As[32][132];
    __shared__ float Bs[32][132];
    const int tid = threadIdx.x;
    const int m0 = blockIdx.y * 128;
    const int n0 = blockIdx.x * 128;
    const int tm = tid >> 4, tn = tid & 15;
    const int lr = tid >> 1, lc = (tid & 1) * 16;

    float acc[8][8];
#pragma unroll
    for (int i = 0; i < 8; ++i)
#pragma unroll
        for (int j = 0; j < 8; ++j) acc[i][j] = 0.f;

    for (int kk = 0; kk < FIN; kk += 32) {
#pragma unroll
        for (int u = 0; u < 4; ++u) {
            float4 av = *reinterpret_cast<const float4*>(
                &x[(size_t)(m0 + lr) * FIN + kk + lc + 4 * u]);
            float4 bv = *reinterpret_cast<const float4*>(
                &wih[(size_t)(n0 + lr) * FIN + kk + lc + 4 * u]);
            As[lc + 4 * u + 0][lr] = av.x;
            As[lc + 4 * u + 1][lr] = av.y;
            As[lc + 4 * u + 2][lr] = av.z;
            As[lc + 4 * u + 3][lr] = av.w;
            Bs[lc + 4 * u + 0][lr] = bv.x;
            Bs[lc + 4 * u + 1][lr] = bv.y;
            Bs[lc + 4 * u + 2][lr] = bv.z;
            Bs[lc + 4 * u + 3][lr] = bv.w;
        }
        __syncthreads();
#pragma unroll
        for (int k = 0; k < 32; ++k) {
            const float4* Ak = reinterpret_cast<const float4*>(&As[k][0]);
            const float4* Bk = reinterpret_cast<const float4*>(&Bs[k][0]);
            float4 a0 = Ak[tm * 2], a1 = Ak[tm * 2 + 1];
            float4 b0 = Bk[tn * 2], b1 = Bk[tn * 2 + 1];
            float a[8] = {a0.x, a0.y, a0.z, a0.w, a1.x, a1.y, a1.z, a1.w};
            float b[8] = {b0.x, b0.y, b0.z, b0.w, b1.x, b1.y, b1.z, b1.w};
#pragma unroll
            for (int i = 0; i < 8; ++i)
#pragma unroll
                for (int j = 0; j < 8; ++j) acc[i][j] = fmaf(a[i], b[j], acc[i][j]);
        }
        __syncthreads();
    }
#pragma unroll
    for (int i = 0; i < 8; ++i) {
        float4 o0 = make_float4(acc[i][0], acc[i][1], acc[i][2], acc[i][3]);
        float4 o1 = make_float4(acc[i][4], acc[i][5], acc[i][6], acc[i][7]);
        float* op = &out[(size_t)(m0 + tm * 8 + i) * HID + n0 + tn * 8];
        *reinterpret_cast<float4*>(op) = o0;
        *reinterpret_cast<float4*>(op + 4) = o1;
    }
}

// ---------------- Phase 2: persistent serial scan ----------------
__device__ __forceinline__ float fast_tanh(float x) {
    // tanh via v_exp_f32: e = 2^(2x*log2e); (e-1)/(e+1). ~1e-6 abs error.
    float cx = fminf(fmaxf(x, -16.f), 16.f);
    float e = __builtin_amdgcn_exp2f(cx * 2.8853900817779268f);
    return (e - 1.f) * __builtin_amdgcn_rcpf(e + 1.f);
}

__device__ __forceinline__ void poll_issue(const ull* __restrict__ src, int lane,
                                           ull (&v)[16]) {
#pragma unroll
    for (int i = 0; i < 16; ++i)
        v[i] = __hip_atomic_load(src + lane + 64 * i, __ATOMIC_RELAXED,
                                 __HIP_MEMORY_SCOPE_AGENT);
}

__device__ __forceinline__ bool tags_ok(const ull (&v)[16], unsigned expect) {
    bool ok = true;
#pragma unroll
    for (int i = 0; i < 16; ++i) ok = ok && ((unsigned)(v[i] >> 32) == expect);
    return ok;
}

// h exchanged as tagged (tag=t+1 hi32 | f32 bits lo32) 8B words, relaxed
// agent-scope atomics (self-validating: no fences needed). Double-buffered.
// launch_bounds(256,1): VGPR cap 512 so the 128-float wreg stays in registers
// (R0 build capped at 100 VGPR and spilled the weight array).
__global__ __launch_bounds__(256, 1) void scan_rnn(
    const float* __restrict__ whh, const float* __restrict__ wgt,
    const float* __restrict__ bih, const float* __restrict__ bhh,
    const float* __restrict__ bb, float* __restrict__ out,
    ull* __restrict__ hbuf) {
    const int lane = threadIdx.x & 63;
    const int wv = threadIdx.x >> 6;
    const int r0 = blockIdx.x * RPB + wv * RPW;
    const int rr = r0 + (lane & 7);

    // W_hh slice in registers: lane covers k = lane + 64*i
    float wreg[RPW][16];
#pragma unroll
    for (int j = 0; j < RPW; ++j)
#pragma unroll
        for (int i = 0; i < 16; ++i)
            wreg[j][i] = whh[(size_t)(r0 + j) * HID + lane + 64 * i];

    const float cw = wgt[rr], cbi = bih[rr], cbh = bhh[rr], cb = bb[rr];
    float xw_cur = out[rr];  // xw row 0 (software-pipelined)

    for (int t = 0; t < T_STEPS; ++t) {
        const ull* src = hbuf + (size_t)(t & 1) * HID;
        ull* dst = hbuf + (size_t)((t + 1) & 1) * HID;
        const unsigned expect = (unsigned)t;

        // Double-batch pipelined poll: always one 16-load batch in flight
        // while checking the older one (in-order vmcnt gives counted waits).
        float hval[16];
        ull va[16], vb[16];
        poll_issue(src, lane, va);
        for (;;) {
            poll_issue(src, lane, vb);
            if (tags_ok(va, expect)) {
#pragma unroll
                for (int i = 0; i < 16; ++i)
                    hval[i] = __uint_as_float((unsigned)va[i]);
                break;
            }
            poll_issue(src, lane, va);
            if (tags_ok(vb, expect)) {
#pragma unroll
                for (int i = 0; i < 16; ++i)
                    hval[i] = __uint_as_float((unsigned)vb[i]);
                break;
            }
        }

        // Prefetch next step's xw now; latency hides under the matvec.
        const size_t nrow = (size_t)(t < T_STEPS - 1 ? t + 1 : t);
        const float xw_nxt = out[nrow * HID + rr];

        float acc[RPW];
#pragma unroll
        for (int j = 0; j < RPW; ++j) acc[j] = 0.f;
#pragma unroll
        for (int i = 0; i < 16; ++i)
#pragma unroll
            for (int j = 0; j < RPW; ++j)
                acc[j] = fmaf(wreg[j][i], hval[i], acc[j]);

        // Reduced butterfly: 3 stages x8 vals, select own row, 3 stages x1.
#pragma unroll
        for (int m = 1; m < 8; m <<= 1)
#pragma unroll
            for (int j = 0; j < RPW; ++j) acc[j] += __shfl_xor(acc[j], m, 64);
        float y = acc[0];
#pragma unroll
        for (int j = 1; j < RPW; ++j) y = ((lane & 7) == j) ? acc[j] : y;
#pragma unroll
        for (int m = 8; m < 64; m <<= 1) y += __shfl_xor(y, m, 64);

        const float arg = fmaf(fmaf(cw, xw_cur, cbh), y, fmaf(cbi, xw_cur, cb));
        const float hn = fast_tanh(arg);
        if (lane < 8) {
            out[(size_t)t * HID + rr] = hn;
            ull pv = (((ull)(unsigned)(t + 1)) << 32) |
                     (ull)__float_as_uint(hn);
            __hip_atomic_store(dst + rr, pv, __ATOMIC_RELAXED,
                               __HIP_MEMORY_SCOPE_AGENT);
        }
        xw_cur = xw_nxt;
    }
}

extern "C" void kernel_launch(void* const* d_in, const int* in_sizes, int n_in,
                              void* d_out, int out_size, void* d_ws, size_t ws_size,
                              hipStream_t stream) {
    const float* x = (const float*)d_in[0];    // [T,1,256]
    const float* wih = (const float*)d_in[1];  // [1024,256]
    const float* whh = (const float*)d_in[2];  // [1024,1024]
    const float* wgt = (const float*)d_in[3];  // [1024]
    const float* bih = (const float*)d_in[4];
    const float* bhh = (const float*)d_in[5];
    const float* bb = (const float*)d_in[6];
    float* out = (float*)d_out;  // [T,1,1024] f32; holds xw between phases

    ull* hbuf = (ull*)d_ws;  // 2*1024*8B = 16 KiB
    hipMemsetAsync(d_ws, 0, 2 * HID * sizeof(ull), stream);

    dim3 ggrid(HID / 128, T_STEPS / 128);
    gemm_xw<<<ggrid, 256, 0, stream>>>(x, wih, out);

    scan_rnn<<<NB, 256, 0, stream>>>(whh, wgt, bih, bhh, bb, out, hbuf);
}

// Round 3
// 74143.439 us; speedup vs baseline: 1.4272x; 1.4272x over previous
//
#include <hip/hip_runtime.h>
#include <hip/hip_bf16.h>
#include <stdint.h>

#define T_STEPS 32768
#define HID 1024
#define FIN 256
#define NB 32            // scan blocks
#define RPB (HID / NB)   // rows per block = 32
#define RPW 8            // rows per wave (4 waves/block)

typedef unsigned long long ull;

// ---------------- Phase 1: xw[t][h] = sum_k x[t][k] * wih[h][k] ----------------
__global__ __launch_bounds__(256) void gemm_xw(const float* __restrict__ x,
                                               const float* __restrict__ wih,
                                               float* __restrict__ out) {
    __shared__ float As[32][132];
    __shared__ float Bs[32][132];
    const int tid = threadIdx.x;
    const int m0 = blockIdx.y * 128;
    const int n0 = blockIdx.x * 128;
    const int tm = tid >> 4, tn = tid & 15;
    const int lr = tid >> 1, lc = (tid & 1) * 16;

    float acc[8][8];
#pragma unroll
    for (int i = 0; i < 8; ++i)
#pragma unroll
        for (int j = 0; j < 8; ++j) acc[i][j] = 0.f;

    for (int kk = 0; kk < FIN; kk += 32) {
#pragma unroll
        for (int u = 0; u < 4; ++u) {
            float4 av = *reinterpret_cast<const float4*>(
                &x[(size_t)(m0 + lr) * FIN + kk + lc + 4 * u]);
            float4 bv = *reinterpret_cast<const float4*>(
                &wih[(size_t)(n0 + lr) * FIN + kk + lc + 4 * u]);
            As[lc + 4 * u + 0][lr] = av.x;
            As[lc + 4 * u + 1][lr] = av.y;
            As[lc + 4 * u + 2][lr] = av.z;
            As[lc + 4 * u + 3][lr] = av.w;
            Bs[lc + 4 * u + 0][lr] = bv.x;
            Bs[lc + 4 * u + 1][lr] = bv.y;
            Bs[lc + 4 * u + 2][lr] = bv.z;
            Bs[lc + 4 * u + 3][lr] = bv.w;
        }
        __syncthreads();
#pragma unroll
        for (int k = 0; k < 32; ++k) {
            const float4* Ak = reinterpret_cast<const float4*>(&As[k][0]);
            const float4* Bk = reinterpret_cast<const float4*>(&Bs[k][0]);
            float4 a0 = Ak[tm * 2], a1 = Ak[tm * 2 + 1];
            float4 b0 = Bk[tn * 2], b1 = Bk[tn * 2 + 1];
            float a[8] = {a0.x, a0.y, a0.z, a0.w, a1.x, a1.y, a1.z, a1.w};
            float b[8] = {b0.x, b0.y, b0.z, b0.w, b1.x, b1.y, b1.z, b1.w};
#pragma unroll
            for (int i = 0; i < 8; ++i)
#pragma unroll
                for (int j = 0; j < 8; ++j) acc[i][j] = fmaf(a[i], b[j], acc[i][j]);
        }
        __syncthreads();
    }
#pragma unroll
    for (int i = 0; i < 8; ++i) {
        float4 o0 = make_float4(acc[i][0], acc[i][1], acc[i][2], acc[i][3]);
        float4 o1 = make_float4(acc[i][4], acc[i][5], acc[i][6], acc[i][7]);
        float* op = &out[(size_t)(m0 + tm * 8 + i) * HID + n0 + tn * 8];
        *reinterpret_cast<float4*>(op) = o0;
        *reinterpret_cast<float4*>(op + 4) = o1;
    }
}

// ---------------- Phase 2: persistent serial scan ----------------
__device__ __forceinline__ float fast_tanh(float x) {
    float cx = fminf(fmaxf(x, -16.f), 16.f);
    float e = __builtin_amdgcn_exp2f(cx * 2.8853900817779268f);
    return (e - 1.f) * __builtin_amdgcn_rcpf(e + 1.f);
}

__device__ __forceinline__ void poll_issue(const ull* __restrict__ src, int lane,
                                           ull (&v)[16]) {
#pragma unroll
    for (int i = 0; i < 16; ++i)
        v[i] = __hip_atomic_load(src + lane + 64 * i, __ATOMIC_RELAXED,
                                 __HIP_MEMORY_SCOPE_AGENT);
}

__device__ __forceinline__ bool tags_ok(const ull (&v)[16], unsigned expect) {
    bool ok = true;
#pragma unroll
    for (int i = 0; i < 16; ++i) ok = ok && ((unsigned)(v[i] >> 32) == expect);
    return ok;
}

// h exchanged as tagged (tag=t+1 hi32 | f32 bits lo32) 8B words, relaxed
// agent-scope atomics. Double-buffered by step parity.
// Per-block poll dedup: wave0 polls the full h (its 64 lanes cover all 1024
// words), writes f32 h into LDS; waves 1-3 take it after one __syncthreads.
// One barrier/step is safe: wave0 can only overwrite hsh after seeing ALL
// tags==t+1, which requires this block's own stores (hence its waves are
// past their hsh reads).
__global__ __launch_bounds__(256, 1) void scan_rnn(
    const float* __restrict__ whh, const float* __restrict__ wgt,
    const float* __restrict__ bih, const float* __restrict__ bhh,
    const float* __restrict__ bb, float* __restrict__ out,
    ull* __restrict__ hbuf) {
    __shared__ float hsh[HID];
    const int lane = threadIdx.x & 63;
    const int wv = threadIdx.x >> 6;
    const int r0 = blockIdx.x * RPB + wv * RPW;
    const int rr = r0 + (lane & 7);

    // W_hh slice: lane covers k = lane + 64*i
    float wreg[RPW][16];
#pragma unroll
    for (int j = 0; j < RPW; ++j)
#pragma unroll
        for (int i = 0; i < 16; ++i)
            wreg[j][i] = whh[(size_t)(r0 + j) * HID + lane + 64 * i];

    const float cw = wgt[rr], cbi = bih[rr], cbh = bhh[rr], cb = bb[rr];
    float xw_cur = out[rr];  // xw row 0 (software-pipelined)

    if (wv == 0) __builtin_amdgcn_s_setprio(1);  // critical wave per block

    for (int t = 0; t < T_STEPS; ++t) {
        const ull* src = hbuf + (size_t)(t & 1) * HID;
        ull* dst = hbuf + (size_t)((t + 1) & 1) * HID;
        const unsigned expect = (unsigned)t;

        float hval[16];
        if (wv == 0) {
            // 2-deep pipelined poll with gentle retry throttle
            ull va[16], vb[16];
            poll_issue(src, lane, va);
            for (;;) {
                poll_issue(src, lane, vb);
                if (tags_ok(va, expect)) {
#pragma unroll
                    for (int i = 0; i < 16; ++i)
                        hval[i] = __uint_as_float((unsigned)va[i]);
                    break;
                }
                __builtin_amdgcn_s_sleep(1);
                poll_issue(src, lane, va);
                if (tags_ok(vb, expect)) {
#pragma unroll
                    for (int i = 0; i < 16; ++i)
                        hval[i] = __uint_as_float((unsigned)vb[i]);
                    break;
                }
                __builtin_amdgcn_s_sleep(1);
            }
            // Publish to siblings ASAP, then compute.
#pragma unroll
            for (int i = 0; i < 16; ++i) hsh[lane + 64 * i] = hval[i];
        }
        __syncthreads();
        if (wv != 0) {
#pragma unroll
            for (int i = 0; i < 16; ++i) hval[i] = hsh[lane + 64 * i];
        }

        // Prefetch next step's xw; latency hides under the matvec.
        const size_t nrow = (size_t)(t < T_STEPS - 1 ? t + 1 : t);
        const float xw_nxt = out[nrow * HID + rr];

        float acc[RPW];
#pragma unroll
        for (int j = 0; j < RPW; ++j) acc[j] = 0.f;
#pragma unroll
        for (int i = 0; i < 16; ++i)
#pragma unroll
            for (int j = 0; j < RPW; ++j)
                acc[j] = fmaf(wreg[j][i], hval[i], acc[j]);

        // 3 stages x8, select own row, 3 stages x1
#pragma unroll
        for (int m = 1; m < 8; m <<= 1)
#pragma unroll
            for (int j = 0; j < RPW; ++j) acc[j] += __shfl_xor(acc[j], m, 64);
        float y = acc[0];
#pragma unroll
        for (int j = 1; j < RPW; ++j) y = ((lane & 7) == j) ? acc[j] : y;
#pragma unroll
        for (int m = 8; m < 64; m <<= 1) y += __shfl_xor(y, m, 64);

        const float arg = fmaf(fmaf(cw, xw_cur, cbh), y, fmaf(cbi, xw_cur, cb));
        const float hn = fast_tanh(arg);
        if (lane < 8) {
            // Tagged store FIRST (critical path), HBM result store second.
            ull pv = (((ull)(unsigned)(t + 1)) << 32) |
                     (ull)__float_as_uint(hn);
            __hip_atomic_store(dst + rr, pv, __ATOMIC_RELAXED,
                               __HIP_MEMORY_SCOPE_AGENT);
            out[(size_t)t * HID + rr] = hn;
        }
        xw_cur = xw_nxt;
    }
}

extern "C" void kernel_launch(void* const* d_in, const int* in_sizes, int n_in,
                              void* d_out, int out_size, void* d_ws, size_t ws_size,
                              hipStream_t stream) {
    const float* x = (const float*)d_in[0];    // [T,1,256]
    const float* wih = (const float*)d_in[1];  // [1024,256]
    const float* whh = (const float*)d_in[2];  // [1024,1024]
    const float* wgt = (const float*)d_in[3];  // [1024]
    const float* bih = (const float*)d_in[4];
    const float* bhh = (const float*)d_in[5];
    const float* bb = (const float*)d_in[6];
    float* out = (float*)d_out;  // [T,1,1024] f32; holds xw between phases

    ull* hbuf = (ull*)d_ws;  // 2*1024*8B = 16 KiB
    hipMemsetAsync(d_ws, 0, 2 * HID * sizeof(ull), stream);

    dim3 ggrid(HID / 128, T_STEPS / 128);
    gemm_xw<<<ggrid, 256, 0, stream>>>(x, wih, out);

    scan_rnn<<<NB, 256, 0, stream>>>(whh, wgt, bih, bhh, bb, out, hbuf);
}